// Round 3
// baseline (168.493 us; speedup 1.0000x reference)
//
#include <hip/hip_runtime.h>
#include <float.h>

// B=32, C=256, HW=1024, K=1024, L=64
// d_out = [ out: 8388608 f32 ][ nearest: 2097152 f32 ]
//
// ws (float units):
//   wT   [256*64] @ 0      : wT[c*64+l] = W_in[l*256+c]  (fp32)
//   cbn  [1024]   @ 16384
//   cbh/cbl ushort[65536] each, wouth/woutl ushort[16384] each @ f17408
//   idx  int[32768] @ f99328
//
// z stash inside d_out's out-region (k3 overwrites it later):
//   zf  f32 [32768][64]    @ out+0
//   zh  ushort [32768][64] @ out+2097152 (as float base)
//   zl  ushort [32768][64] after zh

typedef __attribute__((ext_vector_type(8))) short short8v;
typedef __attribute__((ext_vector_type(4))) float f32x4;

#define MFMA16(A, B, C) __builtin_amdgcn_mfma_f32_16x16x32_bf16((A), (B), (C), 0, 0, 0)

__device__ __forceinline__ unsigned short f2bf(float f) {
    unsigned int u = __float_as_uint(f);
    u += 0x7FFFu + ((u >> 16) & 1u);
    return (unsigned short)(u >> 16);
}
__device__ __forceinline__ float bf2f(unsigned short h) {
    return __uint_as_float(((unsigned int)h) << 16);
}

__global__ void prep_kernel(const float* __restrict__ Win,
                            const float* __restrict__ Wout,
                            const float* __restrict__ cb,
                            float* __restrict__ ws) {
    __shared__ float tile[64][65];
    unsigned short* cbh   = (unsigned short*)(ws + 17408);
    unsigned short* cbl   = cbh + 65536;
    unsigned short* wouth = cbl + 65536;
    unsigned short* woutl = wouth + 16384;
    float* cbn = ws + 16384;
    float* wT  = ws;
    const int blk = blockIdx.x, t = threadIdx.x;

    if (blk < 256) {
        int gid = blk * 256 + t;
        float v = cb[gid];
        unsigned short h = f2bf(v);
        cbh[gid] = h;
        cbl[gid] = f2bf(v - bf2f(h));
        float sq = v * v;
        #pragma unroll
        for (int m = 1; m < 64; m <<= 1) sq += __shfl_xor(sq, m);
        if ((t & 63) == 0) cbn[gid >> 6] = sq;
    } else if (blk < 320) {
        int gid = (blk - 256) * 256 + t;
        float v = Wout[gid];
        unsigned short h = f2bf(v);
        wouth[gid] = h;
        woutl[gid] = f2bf(v - bf2f(h));
    } else {
        int c0 = (blk - 320) * 64;
        #pragma unroll
        for (int it = 0; it < 16; it++) {
            int idx = it * 256 + t;
            int l = idx >> 6, c = idx & 63;
            tile[l][c] = Win[l * 256 + c0 + c];
        }
        __syncthreads();
        #pragma unroll
        for (int it = 0; it < 16; it++) {
            int idx = it * 256 + t;
            int c = idx >> 6, l = idx & 63;
            wT[(c0 + c) * 64 + l] = tile[l][c];
        }
    }
}

// ============ k1: z = W_in @ x + b_in (fp32 VALU, exact), 1024 blocks x 32 pos ============
__launch_bounds__(256, 4)
__global__ void zproj_kernel(const float* __restrict__ x,
                             const float* __restrict__ b_in,
                             const float* __restrict__ ws,
                             float* __restrict__ out) {
    __shared__ __align__(16) float s_x[2][32 * 32];
    __shared__ __align__(16) float s_w[2][32 * 64];
    const int t = threadIdx.x, blk = blockIdx.x;
    const int gp0 = blk * 32;
    const int b = blk >> 5, s0 = (blk & 31) * 32;
    const int lgrp = t & 15, sgrp = t >> 4;   // l quad (4 l), s pair (2 s)
    const float4* x4 = (const float4*)x;

    float* zf = out;
    unsigned short* zh = (unsigned short*)(out + 2097152);
    unsigned short* zl = zh + 2097152;

    float acc[4][2];
    #pragma unroll
    for (int a = 0; a < 4; a++) {
        float bi = b_in[lgrp * 4 + a];
        acc[a][0] = bi; acc[a][1] = bi;
    }

    {   // preload chunk 0
        int c = t >> 3, sq = t & 7;
        *(float4*)&s_x[0][c * 32 + sq * 4] = x4[(b * 256 + c) * 256 + (s0 >> 2) + sq];
        #pragma unroll
        for (int it = 0; it < 8; it++) {
            int idx = it * 256 + t;
            s_w[0][idx] = ws[idx];
        }
    }
    for (int cc = 0; cc < 8; cc++) {
        __syncthreads();
        const int cur = cc & 1, nxt = cur ^ 1;
        if (cc < 7) {
            int c = t >> 3, sq = t & 7;
            *(float4*)&s_x[nxt][c * 32 + sq * 4] =
                x4[(b * 256 + (cc + 1) * 32 + c) * 256 + (s0 >> 2) + sq];
            #pragma unroll
            for (int it = 0; it < 8; it++) {
                int idx = it * 256 + t;
                s_w[nxt][idx] = ws[(cc + 1) * 2048 + idx];
            }
        }
        #pragma unroll 8
        for (int c = 0; c < 32; c++) {
            const float4 wv = *(const float4*)&s_w[cur][c * 64 + lgrp * 4];
            const float2 xv = *(const float2*)&s_x[cur][c * 32 + sgrp * 2];
            acc[0][0] = fmaf(wv.x, xv.x, acc[0][0]);
            acc[1][0] = fmaf(wv.y, xv.x, acc[1][0]);
            acc[2][0] = fmaf(wv.z, xv.x, acc[2][0]);
            acc[3][0] = fmaf(wv.w, xv.x, acc[3][0]);
            acc[0][1] = fmaf(wv.x, xv.y, acc[0][1]);
            acc[1][1] = fmaf(wv.y, xv.y, acc[1][1]);
            acc[2][1] = fmaf(wv.z, xv.y, acc[2][1]);
            acc[3][1] = fmaf(wv.w, xv.y, acc[3][1]);
        }
    }

    #pragma unroll
    for (int i = 0; i < 2; i++) {
        int gs = gp0 + sgrp * 2 + i;
        float4 zv;
        zv.x = acc[0][i]; zv.y = acc[1][i]; zv.z = acc[2][i]; zv.w = acc[3][i];
        *(float4*)&zf[gs * 64 + lgrp * 4] = zv;
        ushort4 hv, lv;
        hv.x = f2bf(zv.x); lv.x = f2bf(zv.x - bf2f(hv.x));
        hv.y = f2bf(zv.y); lv.y = f2bf(zv.y - bf2f(hv.y));
        hv.z = f2bf(zv.z); lv.z = f2bf(zv.z - bf2f(hv.z));
        hv.w = f2bf(zv.w); lv.w = f2bf(zv.w - bf2f(hv.w));
        *(ushort4*)&zh[gs * 64 + lgrp * 4] = hv;
        *(ushort4*)&zl[gs * 64 + lgrp * 4] = lv;
    }
}

// ============ k2: distances (bf16-split MFMA) + top-2 + exact recheck, 1024 blocks x 32 pos ============
__launch_bounds__(256, 4)
__global__ void argmin_kernel(const float* __restrict__ cb,
                              const float* __restrict__ ws,
                              float* __restrict__ out,
                              int* __restrict__ idx_g) {
    __shared__ __align__(16) float s_cbn[1024];
    __shared__ float s_rd1[128], s_rd2[128];
    __shared__ int   s_rk1[128], s_rk2[128];
    __shared__ int   s_ck[64];
    __shared__ float s_e[64];
    __shared__ int   s_ks[32];

    const int t = threadIdx.x, blk = blockIdx.x;
    const int gp0 = blk * 32;
    const int w = t >> 6, lane = t & 63, quad = lane >> 4, n15 = lane & 15;

    const unsigned short* cbh = (const unsigned short*)(ws + 17408);
    const unsigned short* cbl = cbh + 65536;
    const float* zf = out;
    const unsigned short* zh = (const unsigned short*)(out + 2097152);
    const unsigned short* zl = zh + 2097152;

    ((float4*)s_cbn)[t] = ((const float4*)(ws + 16384))[t];

    short8v azh[2][2], azl[2][2];
    #pragma unroll
    for (int mt = 0; mt < 2; mt++)
        #pragma unroll
        for (int kh = 0; kh < 2; kh++) {
            int gs = gp0 + mt * 16 + n15;
            azh[mt][kh] = *(const short8v*)&zh[gs * 64 + kh * 32 + quad * 8];
            azl[mt][kh] = *(const short8v*)&zl[gs * 64 + kh * 32 + quad * 8];
        }
    __syncthreads();

    float d1[2][4], d2[2][4];
    int   k1[2][4], k2[2][4];
    #pragma unroll
    for (int mt = 0; mt < 2; mt++)
        #pragma unroll
        for (int r = 0; r < 4; r++) {
            d1[mt][r] = FLT_MAX; d2[mt][r] = FLT_MAX;
            k1[mt][r] = 0;       k2[mt][r] = 1;
        }

    #pragma unroll 2
    for (int nt = 0; nt < 16; nt++) {
        const int krow = w * 256 + nt * 16 + n15;
        const unsigned short* bhp = cbh + krow * 64 + quad * 8;
        const unsigned short* blp = cbl + krow * 64 + quad * 8;
        short8v bh0 = *(const short8v*)(bhp);
        short8v bh1 = *(const short8v*)(bhp + 32);
        short8v bl0 = *(const short8v*)(blp);
        short8v bl1 = *(const short8v*)(blp + 32);
        float cn = s_cbn[krow];
        #pragma unroll
        for (int mt = 0; mt < 2; mt++) {
            f32x4 acc = {0.f, 0.f, 0.f, 0.f};
            acc = MFMA16(azh[mt][0], bh0, acc);
            acc = MFMA16(azh[mt][1], bh1, acc);
            acc = MFMA16(azl[mt][0], bh0, acc);
            acc = MFMA16(azl[mt][1], bh1, acc);
            acc = MFMA16(azh[mt][0], bl0, acc);
            acc = MFMA16(azh[mt][1], bl1, acc);
            #pragma unroll
            for (int r = 0; r < 4; r++) {
                float d = fmaf(-2.f, acc[r], cn);
                bool lt1 = d < d1[mt][r];
                bool lt2 = d < d2[mt][r];
                float nd1 = fminf(d, d1[mt][r]);
                float nd2 = fminf(fmaxf(d, d1[mt][r]), d2[mt][r]);
                k2[mt][r] = lt1 ? k1[mt][r] : (lt2 ? krow : k2[mt][r]);
                k1[mt][r] = lt1 ? krow : k1[mt][r];
                d1[mt][r] = nd1; d2[mt][r] = nd2;
            }
        }
    }

    // in-wave top-2 reduce over the 16 n15 lanes (lexicographic, lower k on tie)
    #pragma unroll
    for (int mt = 0; mt < 2; mt++)
        #pragma unroll
        for (int r = 0; r < 4; r++) {
            float a1 = d1[mt][r], a2 = d2[mt][r];
            int   b1 = k1[mt][r], b2 = k2[mt][r];
            #pragma unroll
            for (int m = 1; m < 16; m <<= 1) {
                float c1 = __shfl_xor(a1, m), c2 = __shfl_xor(a2, m);
                int   e1 = __shfl_xor(b1, m), e2 = __shfl_xor(b2, m);
                bool aLEc = (a1 < c1) || (a1 == c1 && b1 <= e1);
                float nd1 = aLEc ? a1 : c1;  int nk1 = aLEc ? b1 : e1;
                float xd  = aLEc ? c1 : a1;  int xk  = aLEc ? e1 : b1;
                float yd  = aLEc ? a2 : c2;  int yk  = aLEc ? b2 : e2;
                bool xLEy = (xd < yd) || (xd == yd && xk <= yk);
                a1 = nd1; b1 = nk1;
                a2 = xLEy ? xd : yd;  b2 = xLEy ? xk : yk;
            }
            if (n15 == 0) {
                int pos = mt * 16 + quad * 4 + r;
                s_rd1[pos * 4 + w] = a1; s_rk1[pos * 4 + w] = b1;
                s_rd2[pos * 4 + w] = a2; s_rk2[pos * 4 + w] = b2;
            }
        }
    __syncthreads();

    if (t < 32) {
        float a1 = s_rd1[t * 4], a2 = s_rd2[t * 4];
        int   b1 = s_rk1[t * 4], b2 = s_rk2[t * 4];
        #pragma unroll
        for (int w2 = 1; w2 < 4; w2++) {
            float c1 = s_rd1[t * 4 + w2], c2 = s_rd2[t * 4 + w2];
            int   e1 = s_rk1[t * 4 + w2], e2 = s_rk2[t * 4 + w2];
            bool aLEc = (a1 < c1) || (a1 == c1 && b1 <= e1);
            float nd1 = aLEc ? a1 : c1;  int nk1 = aLEc ? b1 : e1;
            float xd  = aLEc ? c1 : a1;  int xk  = aLEc ? e1 : b1;
            float yd  = aLEc ? a2 : c2;  int yk  = aLEc ? b2 : e2;
            bool xLEy = (xd < yd) || (xd == yd && xk <= yk);
            a1 = nd1; b1 = nk1;
            a2 = xLEy ? xd : yd;  b2 = xLEy ? xk : yk;
        }
        s_ck[t * 2] = b1; s_ck[t * 2 + 1] = b2;
    }
    __syncthreads();

    // exact fp32 recheck of both candidates
    if (t < 64) {
        int pos = t >> 1;
        int k = s_ck[t];
        const float4* cbr = (const float4*)(cb + k * 64);
        const float4* zr  = (const float4*)(zf + (gp0 + pos) * 64);
        float dot = 0.f;
        #pragma unroll
        for (int i = 0; i < 16; i++) {
            float4 zv = zr[i];
            float4 cv = cbr[i];
            dot = fmaf(zv.x, cv.x, dot);
            dot = fmaf(zv.y, cv.y, dot);
            dot = fmaf(zv.z, cv.z, dot);
            dot = fmaf(zv.w, cv.w, dot);
        }
        s_e[t] = fmaf(-2.f, dot, s_cbn[k]);
    }
    __syncthreads();
    if (t < 32) {
        float e1 = s_e[t * 2], e2 = s_e[t * 2 + 1];
        int   c1 = s_ck[t * 2], c2 = s_ck[t * 2 + 1];
        bool take1 = (e1 < e2) || (e1 == e2 && c1 <= c2);
        int sel = take1 ? c1 : c2;
        s_ks[t] = sel;
        idx_g[gp0 + t] = sel;
    }
    __syncthreads();

    // gather nearest = cb[idx] (exact fp32), coalesced
    {
        float4* nearest4 = (float4*)(out + 8388608);
        const float4* cb4 = (const float4*)cb;
        #pragma unroll
        for (int it = 0; it < 2; it++) {
            int idx = it * 256 + t;
            int s = idx >> 4, lq = idx & 15;
            nearest4[(gp0 + s) * 16 + lq] = cb4[s_ks[s] * 16 + lq];
        }
    }
}

// ============ k3: out = W_out @ nearest + b_out (bf16-split MFMA), 1024 blocks x 32 pos ============
__launch_bounds__(256, 4)
__global__ void proj_out_kernel(const float* __restrict__ b_out,
                                const float* __restrict__ ws,
                                const int* __restrict__ idx_g,
                                float* __restrict__ out) {
    __shared__ int   s_idx[32];
    __shared__ float s_bo[256];

    const int t = threadIdx.x, blk = blockIdx.x;
    const int gp0 = blk * 32;
    const int b = blk >> 5, s0 = (blk & 31) * 32;
    const int w = t >> 6, lane = t & 63, quad = lane >> 4, n15 = lane & 15;

    const unsigned short* cbh   = (const unsigned short*)(ws + 17408);
    const unsigned short* cbl   = cbh + 65536;
    const unsigned short* wouth = cbl + 65536;
    const unsigned short* woutl = wouth + 16384;

    if (t < 32) s_idx[t] = idx_g[gp0 + t];
    s_bo[t] = b_out[t];
    __syncthreads();

    short8v ah[2][2], al[2][2];
    #pragma unroll
    for (int mt = 0; mt < 2; mt++) {
        int k = s_idx[mt * 16 + n15];
        #pragma unroll
        for (int kh = 0; kh < 2; kh++) {
            ah[mt][kh] = *(const short8v*)(cbh + k * 64 + kh * 32 + quad * 8);
            al[mt][kh] = *(const short8v*)(cbl + k * 64 + kh * 32 + quad * 8);
        }
    }
    #pragma unroll
    for (int nt = 0; nt < 4; nt++) {
        int c = w * 64 + nt * 16 + n15;
        const unsigned short* bhp = wouth + c * 64 + quad * 8;
        const unsigned short* blp = woutl + c * 64 + quad * 8;
        short8v bh0 = *(const short8v*)(bhp);
        short8v bh1 = *(const short8v*)(bhp + 32);
        short8v bl0 = *(const short8v*)(blp);
        short8v bl1 = *(const short8v*)(blp + 32);
        float bo = s_bo[c];
        #pragma unroll
        for (int mt = 0; mt < 2; mt++) {
            f32x4 acc = {0.f, 0.f, 0.f, 0.f};
            acc = MFMA16(ah[mt][0], bh0, acc);
            acc = MFMA16(ah[mt][1], bh1, acc);
            acc = MFMA16(al[mt][0], bh0, acc);
            acc = MFMA16(al[mt][1], bh1, acc);
            acc = MFMA16(ah[mt][0], bl0, acc);
            acc = MFMA16(ah[mt][1], bl1, acc);
            float4 o;
            o.x = acc[0] + bo; o.y = acc[1] + bo; o.z = acc[2] + bo; o.w = acc[3] + bo;
            *(float4*)&out[(b * 256 + c) * 1024 + s0 + mt * 16 + quad * 4] = o;
        }
    }
}

extern "C" void kernel_launch(void* const* d_in, const int* in_sizes, int n_in,
                              void* d_out, int out_size, void* d_ws, size_t ws_size,
                              hipStream_t stream) {
    const float* x    = (const float*)d_in[0];
    const float* cb   = (const float*)d_in[1];
    const float* Win  = (const float*)d_in[2];
    const float* bin  = (const float*)d_in[3];
    const float* Wout = (const float*)d_in[4];
    const float* bout = (const float*)d_in[5];
    float* out = (float*)d_out;
    float* ws  = (float*)d_ws;
    int* idx_g = (int*)(ws + 99328);

    prep_kernel<<<324, 256, 0, stream>>>(Win, Wout, cb, ws);
    zproj_kernel<<<1024, 256, 0, stream>>>(x, bin, ws, out);
    argmin_kernel<<<1024, 256, 0, stream>>>(cb, ws, out, idx_g);
    proj_out_kernel<<<1024, 256, 0, stream>>>(bout, ws, idx_g, out);
}